// Round 1
// baseline (412.276 us; speedup 1.0000x reference)
//
#include <hip/hip_runtime.h>
#include <hip/hip_bf16.h>

// Reference is the identity on x (float32): pywt.waverec([cA], ...) with a
// single-entry coeff list returns cA unchanged. So this is a pure 256 MiB
// device-to-device copy. Memory-bound: target ~85 us at 6.3 TB/s achievable.

__global__ __launch_bounds__(256) void identity_copy_f4(
    const float4* __restrict__ in, float4* __restrict__ out, long long n4) {
    long long i = (long long)blockIdx.x * blockDim.x + threadIdx.x;
    if (i < n4) {
        out[i] = in[i];
    }
}

extern "C" void kernel_launch(void* const* d_in, const int* in_sizes, int n_in,
                              void* d_out, int out_size, void* d_ws, size_t ws_size,
                              hipStream_t stream) {
    const float* x = (const float*)d_in[0];
    float* out = (float*)d_out;

    long long n = (long long)in_sizes[0];   // 64 * 2^20 = 67,108,864 floats
    long long n4 = n / 4;                   // divisible by 4

    const int block = 256;
    long long grid = (n4 + block - 1) / block;

    identity_copy_f4<<<dim3((unsigned)grid), dim3(block), 0, stream>>>(
        (const float4*)x, (float4*)out, n4);

    // Handle any non-multiple-of-4 tail (not expected here: n % 4 == 0),
    // done scalar in a tiny second launch only if needed.
    long long tail = n - n4 * 4;
    if (tail > 0) {
        // tail < 4 — a single-block scalar cleanup
        // (unused for this problem; kept for robustness)
        struct TailKern {
            static __global__ void run(const float* in, float* out, long long start, long long n) {
                long long i = start + threadIdx.x;
                if (i < n) out[i] = in[i];
            }
        };
        hipLaunchKernelGGL(TailKern::run, dim3(1), dim3(64), 0, stream, x, out, n4 * 4, n);
    }
}